// Round 12
// baseline (185.558 us; speedup 1.0000x reference)
//
#include <hip/hip_runtime.h>
#include <float.h>
#include <stdint.h>

#define T_ 2048
#define DG 256   // folded/group width: 4 groups * 64

typedef _Float16 half8 __attribute__((ext_vector_type(8)));
typedef _Float16 half4v __attribute__((ext_vector_type(4)));
typedef __fp16 fp16x2 __attribute__((ext_vector_type(2)));
typedef float f32x4 __attribute__((ext_vector_type(4)));
typedef float f32x16 __attribute__((ext_vector_type(16)));
typedef unsigned uint2v __attribute__((ext_vector_type(2)));

__device__ __forceinline__ void gload16(const void* g, void* l) {
  __builtin_amdgcn_global_load_lds(
      (const __attribute__((address_space(1))) unsigned int*)g,
      (__attribute__((address_space(3))) unsigned int*)l, 16, 0, 0);
}
#define WAIT_LGKM0() do { asm volatile("s_waitcnt lgkmcnt(0)" ::: "memory"); __builtin_amdgcn_sched_barrier(0); } while (0)

// lane<->lane^32 exchange, all-VALU (v_permlane32_swap_b32)
__device__ __forceinline__ float cross32(float x, int g) {
  unsigned u = __builtin_bit_cast(unsigned, x);
  uint2v r = __builtin_amdgcn_permlane32_swap(u, u, false, false);
  return __builtin_bit_cast(float, g ? r[0] : r[1]);
}

__device__ __forceinline__ half8 cvt8(float4 a, float4 b) {
  union { unsigned u[4]; half8 h; } r;
  r.u[0] = __builtin_bit_cast(unsigned, __builtin_amdgcn_cvt_pkrtz(a.x, a.y));
  r.u[1] = __builtin_bit_cast(unsigned, __builtin_amdgcn_cvt_pkrtz(a.z, a.w));
  r.u[2] = __builtin_bit_cast(unsigned, __builtin_amdgcn_cvt_pkrtz(b.x, b.y));
  r.u[3] = __builtin_bit_cast(unsigned, __builtin_amdgcn_cvt_pkrtz(b.z, b.w));
  return r.h;
}

// ---- prep_w: Wt[768][1024] fp16 (folded Wq | Wk | Wv, transposed) + bcat[768] f32 ----
__global__ __launch_bounds__(256) void prep_w(
    const float* __restrict__ Wq, const float* __restrict__ bq,
    const float* __restrict__ Wk, const float* __restrict__ bk,
    const float* __restrict__ Wv, const float* __restrict__ bv,
    _Float16* __restrict__ Wt, float* __restrict__ bcat) {
  for (int idx = blockIdx.x * 256 + threadIdx.x; idx < 786432; idx += 768 * 256) {
    int n = idx >> 10, k = idx & 1023;
    float v;
    if (n < 256)      v = Wq[k * 1024 + n] + Wq[k * 1024 + n + 256]
                        + Wq[k * 1024 + n + 512] + Wq[k * 1024 + n + 768];
    else if (n < 512) v = Wk[k * 256 + n - 256];
    else              v = Wv[k * 256 + n - 512];
    Wt[idx] = (_Float16)v;
    if (k == 0) {
      float bb;
      if (n < 256)      bb = bq[n] + bq[n + 256] + bq[n + 512] + bq[n + 768];
      else if (n < 512) bb = bk[n - 256];
      else              bb = bv[n - 512];
      bcat[n] = bb;
    }
  }
}

// ---- qkv_gemm: x[16384x1024] fp32 @ Wt^T -> Q fp16(x log2e) | K frag-major | V frag-major
// 128x256 tile (grid 128 x 3 types); A reg-staged fp32->fp16 (cvt once), B via gload_lds.
__global__ __launch_bounds__(256) void qkv_gemm(
    const float* __restrict__ x, const _Float16* __restrict__ Wt,
    const float* __restrict__ bcat,
    _Float16* __restrict__ Qh, _Float16* __restrict__ Kf, _Float16* __restrict__ Vf) {
  __shared__ __align__(16) uint8_t smem[49152];   // 2 x (A 8KB + B 16KB) fp16
  const int tid = threadIdx.x;
  const int w = tid >> 6, l = tid & 63;
  const int wr = w >> 1, wc = w & 1;
  const int lr = l & 15, lk = l >> 4;
  const int m0 = blockIdx.x * 128;
  const int by = blockIdx.y;          // 0=Q, 1=K, 2=V
  const int n0 = by * 256;

  f32x4 acc[4][8] = {};

  const int arow = tid >> 1;          // 0..127
  const int ag   = (tid & 1) * 2;     // logical granule base (of 4 per row)

  auto loadA = [&](int k0, float4* fr) {
    const float4* src = (const float4*)(x + (size_t)(m0 + arow) * 1024 + k0 + ag * 8);
    fr[0] = src[0]; fr[1] = src[1]; fr[2] = src[2]; fr[3] = src[3];
  };
  auto writeA = [&](int buf, const float4* fr) {
    uint8_t* Ab = smem + buf * 24576;
    *(half8*)(Ab + arow * 64 + (((ag + 0) ^ (arow & 3)) << 4)) = cvt8(fr[0], fr[1]);
    *(half8*)(Ab + arow * 64 + (((ag + 1) ^ (arow & 3)) << 4)) = cvt8(fr[2], fr[3]);
  };
  auto stageB = [&](int k0, int buf) {
    uint8_t* Bb = smem + buf * 24576 + 8192;
#pragma unroll
    for (int i = 0; i < 4; ++i) {
      int si = i * 256 + tid;
      int row = si >> 2, p = si & 3;
      gload16(Wt + (size_t)(n0 + row) * 1024 + k0 + ((p ^ (row & 3)) << 3), Bb + si * 16);
    }
  };

  {
    float4 fr[4];
    loadA(0, fr);
    stageB(0, 0);
    writeA(0, fr);
  }
  __syncthreads();

  for (int kt = 0; kt < 32; ++kt) {
    int cur = kt & 1;
    float4 nf[4];
    if (kt < 31) { loadA((kt + 1) * 32, nf); stageB((kt + 1) * 32, cur ^ 1); }
    const uint8_t* Ab = smem + cur * 24576;
    const uint8_t* Bb = Ab + 8192;
    half8 af[4], bf[8];
#pragma unroll
    for (int mi = 0; mi < 4; ++mi) {
      int row = wr * 64 + mi * 16 + lr;
      af[mi] = *(const half8*)(Ab + row * 64 + ((lk ^ (row & 3)) << 4));
    }
#pragma unroll
    for (int ni = 0; ni < 8; ++ni) {
      int row = wc * 128 + ni * 16 + lr;
      bf[ni] = *(const half8*)(Bb + row * 64 + ((lk ^ (row & 3)) << 4));
    }
#pragma unroll
    for (int mi = 0; mi < 4; ++mi)
#pragma unroll
      for (int ni = 0; ni < 8; ++ni)
        acc[mi][ni] = __builtin_amdgcn_mfma_f32_16x16x32_f16(af[mi], bf[ni], acc[mi][ni], 0, 0, 0);
    if (kt < 31) writeA(cur ^ 1, nf);
    __syncthreads();
  }

  // ---- epilogues (C: col = lane&15 (n), row = (lane>>4)*4 + r (m)) ----
  if (by == 0) {
#pragma unroll
    for (int mi = 0; mi < 4; ++mi)
#pragma unroll
      for (int ni = 0; ni < 8; ++ni) {
        int nl = wc * 128 + ni * 16 + lr;
        int mg = m0 + wr * 64 + mi * 16 + lk * 4;
        float bias = bcat[nl];
#pragma unroll
        for (int r = 0; r < 4; ++r)
          Qh[(size_t)(mg + r) * DG + nl] = (_Float16)((acc[mi][ni][r] + bias) * 1.44269504f);
      }
  } else if (by == 2) {
#pragma unroll
    for (int mi = 0; mi < 4; ++mi)
#pragma unroll
      for (int ni = 0; ni < 8; ++ni) {
        int nl = wc * 128 + ni * 16 + lr;
        int mg = m0 + wr * 64 + mi * 16 + lk * 4;
        float bias = bcat[512 + nl];
        // V fragment-major: [b][st][dt][half hs][lane][8 j(t)]
        int dt = nl >> 5, lnv = nl & 31;
        int bb = mg >> 11, t0 = mg & 2047;
        int st = t0 >> 5, sp = t0 & 31;
        int hs = sp >> 4, gg = (sp >> 3) & 1, j0 = sp & 7;
        size_t idx = (size_t)(((bb * 64 + st) * 8 + dt) * 2 + hs) * 512
                   + (gg * 32 + lnv) * 8 + j0;
        half4v h;
#pragma unroll
        for (int r = 0; r < 4; ++r) h[r] = (_Float16)(acc[mi][ni][r] + bias);
        *(half4v*)(Vf + idx) = h;
      }
  } else {
    // K -> fragment-major via two 32KB LDS bounce phases (d-halves)
#pragma unroll
    for (int h = 0; h < 2; ++h) {
      if (wc == h) {
#pragma unroll
        for (int mi = 0; mi < 4; ++mi)
#pragma unroll
          for (int ni = 0; ni < 8; ++ni) {
            int dl = ni * 16 + lr;               // 0..127 within this half
            float bias = bcat[256 + h * 128 + dl];
#pragma unroll
            for (int r = 0; r < 4; ++r) {
              int t = wr * 64 + mi * 16 + lk * 4 + r;
              *(_Float16*)(smem + t * 256 + ((dl * 2) ^ ((t & 7) << 4))) =
                  (_Float16)(acc[mi][ni][r] + bias);
            }
          }
      }
      __syncthreads();
#pragma unroll
      for (int i = 0; i < 8; ++i) {
        int p = i * 256 + tid;
        int ln = p & 31, g = (p >> 5) & 1, cl = (p >> 6) & 7, st = p >> 9;
        int t = st * 32 + ln;
        int d0 = cl * 16 + g * 8;
        half8 v = *(const half8*)(smem + t * 256 + ((d0 * 2) ^ ((t & 7) << 4)));
        int tg = m0 + t;
        int bb = tg >> 11, stg = (tg & 2047) >> 5;
        int cc = h * 8 + cl;
        *(half8*)(Kf + ((size_t)(((bb * 64 + stg) * 16 + cc) * 2 + g) * 32 + ln) * 8) = v;
      }
      __syncthreads();
    }
  }
}

// ---- attn_main: 4 waves/WG d-split; K & V frag-major direct from L2; LDS = 20KB Sx only
// split-K: tiles 0-15 nc=1, 16-31 nc=2, 32-47 nc=3, 48-63 nc=4 (chunks <= 16 iters)
__global__ __launch_bounds__(256, 4) void attn_main(
    const _Float16* __restrict__ Qg, const _Float16* __restrict__ Kf,
    const _Float16* __restrict__ Vf, float* __restrict__ out,
    _Float16* __restrict__ PO, float* __restrict__ ML) {
  __shared__ float Sx[5120];      // [wv*64 + lane][20 floats] (16 data + pad)
  const int tid = threadIdx.x;
  const int wv = tid >> 6;        // 0..3
  const int l  = tid & 63;
  const int g  = l >> 5;
  const int ln = l & 31;
  const int id = blockIdx.x;
  const int b  = id & 7;                  // batch -> XCD pinning
  const int u  = id >> 3;                 // 0..159
  int tt, nc, c;
  if (u < 16)      { tt = u;                  nc = 1; c = 0; }
  else if (u < 48) { tt = 16 + ((u - 16) >> 1); nc = 2; c = (u - 16) & 1; }
  else if (u < 96) { tt = 32 + (u - 48) / 3;  nc = 3; c = (u - 48) % 3; }
  else             { tt = 48 + ((u - 96) >> 2); nc = 4; c = (u - 96) & 3; }
  const int len = (tt + nc) / nc;
  const int lo  = c * len;
  const int hi  = min(lo + len, tt + 1);
  const int q0  = tt * 32;

  const _Float16* Kfb = Kf + (size_t)b * 524288;
  const _Float16* Vfb = Vf + (size_t)b * 524288;

  const _Float16* Qrow = Qg + ((size_t)(b * T_ + q0 + ln)) * DG + wv * 64 + 8 * g;
  half8 qf[4];
#pragma unroll
  for (int j = 0; j < 4; ++j) qf[j] = *(const half8*)(Qrow + j * 16);

  f32x16 o0 = {}, o1 = {};        // output-d blocks dt = 2wv, 2wv+1
  float m_r = -1e30f, l_r = 0.0f;

  for (int kt = lo; kt < hi; ++kt) {
    // ---- K fragments: coalesced (frag-major) ----
    const _Float16* kbase = Kfb + (size_t)(kt * 16 + 4 * wv) * 512 + l * 8;
    half8 kf0 = *(const half8*)(kbase);
    half8 kf1 = *(const half8*)(kbase + 512);
    half8 kf2 = *(const half8*)(kbase + 1024);
    half8 kf3 = *(const half8*)(kbase + 1536);
    // ---- V fragments: coalesced, consumed after softmax ----
    const _Float16* vbase = Vfb + (size_t)(kt * 8 + 2 * wv) * 1024 + l * 8;
    half8 va0 = *(const half8*)(vbase);
    half8 va1 = *(const half8*)(vbase + 512);
    half8 vb0 = *(const half8*)(vbase + 1024);
    half8 vb1 = *(const half8*)(vbase + 1536);

    f32x16 s_acc = {};
    __builtin_amdgcn_s_setprio(1);
    s_acc = __builtin_amdgcn_mfma_f32_32x32x16_f16(kf0, qf[0], s_acc, 0, 0, 0);
    s_acc = __builtin_amdgcn_mfma_f32_32x32x16_f16(kf1, qf[1], s_acc, 0, 0, 0);
    s_acc = __builtin_amdgcn_mfma_f32_32x32x16_f16(kf2, qf[2], s_acc, 0, 0, 0);
    s_acc = __builtin_amdgcn_mfma_f32_32x32x16_f16(kf3, qf[3], s_acc, 0, 0, 0);
    __builtin_amdgcn_s_setprio(0);

    // ---- publish partial scores, exchange ----
    {
      float* myrow = Sx + (wv * 64 + l) * 20;
#pragma unroll
      for (int i = 0; i < 4; ++i)
        *(f32x4*)(myrow + 4 * i) = *(((const f32x4*)&s_acc) + i);
    }
    WAIT_LGKM0();
    __builtin_amdgcn_s_barrier();

    f32x4 sv[4];
#pragma unroll
    for (int i = 0; i < 4; ++i) sv[i] = *(((const f32x4*)&s_acc) + i);
#pragma unroll
    for (int wo = 0; wo < 4; ++wo) {
      if (wo == wv) continue;
      const float* prow = Sx + (wo * 64 + l) * 20;
#pragma unroll
      for (int i = 0; i < 4; ++i) sv[i] += *(const f32x4*)(prow + 4 * i);
    }
    float s[16];
#pragma unroll
    for (int r = 0; r < 16; ++r) s[r] = sv[r >> 2][r & 3];

    if (kt == tt) {                  // causal mask (last chunk only)
#pragma unroll
      for (int r = 0; r < 16; ++r) {
        int srow = (r & 3) + 8 * (r >> 2) + 4 * g;
        if (srow > ln) s[r] = -1e30f;
      }
    }
    // ---- softmax (replicated across waves, bit-identical) ----
    float pmax = s[0];
#pragma unroll
    for (int r = 1; r < 16; ++r) pmax = fmaxf(pmax, s[r]);
    pmax = fmaxf(pmax, cross32(pmax, g));
    if (!__all(pmax <= m_r + 8.0f)) {   // defer-max rescale (T13)
      float mnew = fmaxf(m_r, pmax);
      float sc = __builtin_amdgcn_exp2f(m_r - mnew);
      l_r *= sc;
#pragma unroll
      for (int r = 0; r < 16; ++r) { o0[r] *= sc; o1[r] *= sc; }
      m_r = mnew;
    }
    float p[16]; float psum = 0.0f;
#pragma unroll
    for (int r = 0; r < 16; ++r) { p[r] = __builtin_amdgcn_exp2f(s[r] - m_r); psum += p[r]; }
    l_r += psum + cross32(psum, g);

    // ---- P -> fp16 B-fragments: cvt_pkrtz + 4 permlane32_swap ----
    unsigned ph[8];
#pragma unroll
    for (int i = 0; i < 8; ++i) {
      fp16x2 t2 = __builtin_amdgcn_cvt_pkrtz(p[2 * i], p[2 * i + 1]);
      ph[i] = __builtin_bit_cast(unsigned, t2);
    }
    union U { unsigned u[4]; half8 h; };
    U f0, f1;
    {
      uint2v r02 = __builtin_amdgcn_permlane32_swap(ph[0], ph[2], false, false);
      uint2v r13 = __builtin_amdgcn_permlane32_swap(ph[1], ph[3], false, false);
      uint2v r46 = __builtin_amdgcn_permlane32_swap(ph[4], ph[6], false, false);
      uint2v r57 = __builtin_amdgcn_permlane32_swap(ph[5], ph[7], false, false);
      f0.u[0] = r02[0]; f0.u[2] = r02[1];
      f0.u[1] = r13[0]; f0.u[3] = r13[1];
      f1.u[0] = r46[0]; f1.u[2] = r46[1];
      f1.u[1] = r57[0]; f1.u[3] = r57[1];
    }

    // ---- PV for this wave's output-d slice ----
    __builtin_amdgcn_s_setprio(1);
    o0 = __builtin_amdgcn_mfma_f32_32x32x16_f16(va0, f0.h, o0, 0, 0, 0);
    o0 = __builtin_amdgcn_mfma_f32_32x32x16_f16(va1, f1.h, o0, 0, 0, 0);
    o1 = __builtin_amdgcn_mfma_f32_32x32x16_f16(vb0, f0.h, o1, 0, 0, 0);
    o1 = __builtin_amdgcn_mfma_f32_32x32x16_f16(vb1, f1.h, o1, 0, 0, 0);
    __builtin_amdgcn_s_setprio(0);

    __builtin_amdgcn_s_barrier();    // Sx safe to overwrite next iter
  }

  // ---- epilogue: per-wave chunk transpose in own Sx region ----
  float* chunk = Sx + wv * 1280;     // [32 q][33 d] fp32, wave-private
  if (nc == 1) {
    float inv = 1.0f / (l_r * 8.0f);           // includes post-softmax /sqrt(64)
    float* ob = out + ((size_t)(b * T_ + q0)) * 1024;
#pragma unroll
    for (int dtl = 0; dtl < 2; ++dtl) {
      const f32x16& oo = dtl ? o1 : o0;
      WAIT_LGKM0();
#pragma unroll
      for (int r = 0; r < 16; ++r) {
        int dl = (r & 3) + 8 * (r >> 2) + 4 * g;
        chunk[ln * 33 + dl] = oo[r] * inv;
      }
      WAIT_LGKM0();
#pragma unroll
      for (int rr = 0; rr < 2; ++rr) {
        int qq = (l >> 2) + 16 * rr;
        int cp = (l & 3) * 8;
        float vv[8];
#pragma unroll
        for (int jj = 0; jj < 8; ++jj) vv[jj] = chunk[qq * 33 + cp + jj];
        float4 w0 = make_float4(vv[0], vv[1], vv[2], vv[3]);
        float4 w1 = make_float4(vv[4], vv[5], vv[6], vv[7]);
        float* orow = ob + (size_t)qq * 1024 + (2 * wv + dtl) * 32 + cp;
#pragma unroll
        for (int rep = 0; rep < 4; ++rep) {
          *(float4*)(orow + rep * 256)     = w0;
          *(float4*)(orow + rep * 256 + 4) = w1;
        }
      }
    }
  } else {
    int ti = tt - 16;
    int off = (ti < 16) ? ti * 2 : (ti < 32) ? 32 + (ti - 16) * 3 : 80 + (ti - 32) * 4;
    int slot = b * 144 + off + c;
    _Float16* P = PO + (size_t)slot * 8192;
#pragma unroll
    for (int dtl = 0; dtl < 2; ++dtl) {
      const f32x16& oo = dtl ? o1 : o0;
      WAIT_LGKM0();
#pragma unroll
      for (int r = 0; r < 16; ++r) {
        int dl = (r & 3) + 8 * (r >> 2) + 4 * g;
        chunk[ln * 33 + dl] = oo[r];
      }
      WAIT_LGKM0();
#pragma unroll
      for (int rr = 0; rr < 2; ++rr) {
        int qq = (l >> 2) + 16 * rr;
        int cp = (l & 3) * 8;
        half8 hv;
#pragma unroll
        for (int jj = 0; jj < 8; ++jj) hv[jj] = (_Float16)chunk[qq * 33 + cp + jj];
        *(half8*)(P + qq * 256 + (2 * wv + dtl) * 32 + cp) = hv;
      }
    }
    if (wv == 0 && l < 32) {
      ML[(size_t)slot * 64 + l]      = m_r;
      ML[(size_t)slot * 64 + 32 + l] = l_r;
    }
  }
}

// ---- attn_merge: combine nc in {2,3,4} fp16 partials, normalize, x4 replicate ----
__global__ __launch_bounds__(256) void attn_merge(
    const _Float16* __restrict__ PO, const float* __restrict__ ML,
    float* __restrict__ out) {
  const int id = blockIdx.x;           // 384 = 8 b x 48 tiles
  const int b = id & 7, ti = id >> 3;
  const int tt = 16 + ti;
  const int nc = (ti < 16) ? 2 : (ti < 32) ? 3 : 4;
  const int off = (ti < 16) ? ti * 2 : (ti < 32) ? 32 + (ti - 16) * 3 : 80 + (ti - 32) * 4;
  const int slot0 = b * 144 + off;
  const int tid = threadIdx.x;
  const int row = tid >> 3, cb = tid & 7;

  float mj[4], lj[4];
  float M = -1e30f;
#pragma unroll
  for (int j = 0; j < 4; ++j)
    if (j < nc) {
      mj[j] = ML[(size_t)(slot0 + j) * 64 + row];
      lj[j] = ML[(size_t)(slot0 + j) * 64 + 32 + row];
      M = fmaxf(M, mj[j]);
    }
  float sc[4], lsum = 0.0f;
#pragma unroll
  for (int j = 0; j < 4; ++j)
    if (j < nc) { sc[j] = __builtin_amdgcn_exp2f(mj[j] - M); lsum += lj[j] * sc[j]; }
  float inv = 1.0f / (lsum * 8.0f);    // includes post-softmax /sqrt(64)

  float acc[32] = {};
#pragma unroll
  for (int j = 0; j < 4; ++j)
    if (j < nc) {
      const _Float16* P = PO + (size_t)(slot0 + j) * 8192 + row * 256 + cb * 32;
      float s = sc[j];
#pragma unroll
      for (int q = 0; q < 4; ++q) {
        half8 h = *(const half8*)(P + q * 8);
#pragma unroll
        for (int e = 0; e < 8; ++e) acc[q * 8 + e] += s * (float)h[e];
      }
    }
  float* orow = out + ((size_t)(b * T_ + tt * 32 + row)) * 1024 + cb * 32;
#pragma unroll
  for (int q = 0; q < 8; ++q) {
    float4 v;
    v.x = acc[q * 4 + 0] * inv; v.y = acc[q * 4 + 1] * inv;
    v.z = acc[q * 4 + 2] * inv; v.w = acc[q * 4 + 3] * inv;
#pragma unroll
    for (int rep = 0; rep < 4; ++rep)
      *(float4*)(orow + rep * 256 + q * 4) = v;
  }
}

extern "C" void kernel_launch(void* const* d_in, const int* in_sizes, int n_in,
                              void* d_out, int out_size, void* d_ws, size_t ws_size,
                              hipStream_t stream) {
  const float* x  = (const float*)d_in[0];
  const float* Wq = (const float*)d_in[1];
  const float* bq = (const float*)d_in[2];
  const float* Wk = (const float*)d_in[3];
  const float* bk = (const float*)d_in[4];
  const float* Wv = (const float*)d_in[5];
  const float* bv = (const float*)d_in[6];
  float* out = (float*)d_out;
  char* ws = (char*)d_ws;
  _Float16* Wt   = (_Float16*)ws;                         // 1.5 MB
  float*    bcat = (float*)(ws + 0x180000);               // 4 KB
  _Float16* Qh   = (_Float16*)(ws + 0x181000);            // 8 MB
  _Float16* Kf   = (_Float16*)(ws + 0x981000);            // 8 MB fragment-major K
  _Float16* Vf   = (_Float16*)(ws + 0x1181000);           // 8 MB fragment-major V
  _Float16* PO   = (_Float16*)(ws + 0x1981000);           // 18.9 MB partials
  float*    ML   = (float*)(ws + 0x1981000 + 0x1200000);  // 0.3 MB

  prep_w<<<768, 256, 0, stream>>>(Wq, bq, Wk, bk, Wv, bv, Wt, bcat);
  qkv_gemm<<<dim3(128, 3), 256, 0, stream>>>(x, Wt, bcat, Qh, Kf, Vf);
  attn_main<<<1280, 256, 0, stream>>>(Qh, Kf, Vf, out, PO, ML);
  attn_merge<<<384, 256, 0, stream>>>(PO, ML, out);
}

// Round 13
// 159.138 us; speedup vs baseline: 1.1660x; 1.1660x over previous
//
#include <hip/hip_runtime.h>
#include <float.h>
#include <stdint.h>

#define T_ 2048
#define DG 256   // folded/group width: 4 groups * 64

typedef _Float16 half8 __attribute__((ext_vector_type(8)));
typedef _Float16 half4v __attribute__((ext_vector_type(4)));
typedef __fp16 fp16x2 __attribute__((ext_vector_type(2)));
typedef float f32x4 __attribute__((ext_vector_type(4)));
typedef float f32x16 __attribute__((ext_vector_type(16)));
typedef unsigned uint2v __attribute__((ext_vector_type(2)));

__device__ __forceinline__ void gload16(const void* g, void* l) {
  __builtin_amdgcn_global_load_lds(
      (const __attribute__((address_space(1))) unsigned int*)g,
      (__attribute__((address_space(3))) unsigned int*)l, 16, 0, 0);
}
#define WAIT_LGKM0() do { asm volatile("s_waitcnt lgkmcnt(0)" ::: "memory"); __builtin_amdgcn_sched_barrier(0); } while (0)

// lane<->lane^32 exchange, all-VALU (v_permlane32_swap_b32)
__device__ __forceinline__ float cross32(float x, int g) {
  unsigned u = __builtin_bit_cast(unsigned, x);
  uint2v r = __builtin_amdgcn_permlane32_swap(u, u, false, false);
  return __builtin_bit_cast(float, g ? r[0] : r[1]);
}

// ---- prep_w: Wt[768][1024] fp16 (folded Wq | Wk | Wv, transposed) + bcat[768] f32 ----
__global__ __launch_bounds__(256) void prep_w(
    const float* __restrict__ Wq, const float* __restrict__ bq,
    const float* __restrict__ Wk, const float* __restrict__ bk,
    const float* __restrict__ Wv, const float* __restrict__ bv,
    _Float16* __restrict__ Wt, float* __restrict__ bcat) {
  for (int idx = blockIdx.x * 256 + threadIdx.x; idx < 786432; idx += 768 * 256) {
    int n = idx >> 10, k = idx & 1023;
    float v;
    if (n < 256)      v = Wq[k * 1024 + n] + Wq[k * 1024 + n + 256]
                        + Wq[k * 1024 + n + 512] + Wq[k * 1024 + n + 768];
    else if (n < 512) v = Wk[k * 256 + n - 256];
    else              v = Wv[k * 256 + n - 512];
    Wt[idx] = (_Float16)v;
    if (k == 0) {
      float bb;
      if (n < 256)      bb = bq[n] + bq[n + 256] + bq[n + 512] + bq[n + 768];
      else if (n < 512) bb = bk[n - 256];
      else              bb = bv[n - 512];
      bcat[n] = bb;
    }
  }
}

// ---- qkv_gemm: x[16384x1024] fp32 @ Wt^T -> Q fp16(x log2e) | K frag-major | V frag-major
// 128x256 tile, grid (128,3); A fp32 + B fp16 both via global_load_lds (r9-proven),
// A converted to fp16 at fragment read (RNE).
__global__ __launch_bounds__(256) void qkv_gemm(
    const float* __restrict__ x, const _Float16* __restrict__ Wt,
    const float* __restrict__ bcat,
    _Float16* __restrict__ Qh, _Float16* __restrict__ Kf, _Float16* __restrict__ Vf) {
  __shared__ __align__(16) uint8_t smem[65536];   // 2 x (A 16KB fp32 + B 16KB fp16)
  const int tid = threadIdx.x;
  const int w = tid >> 6, l = tid & 63;
  const int wr = w >> 1, wc = w & 1;
  const int lr = l & 15, lk = l >> 4;
  const int m0 = blockIdx.x * 128;
  const int by = blockIdx.y;          // 0=Q, 1=K, 2=V
  const int n0 = by * 256;

  f32x4 acc[4][8] = {};

  auto stage = [&](int k0, int buf) {
    uint8_t* Ab = smem + buf * 32768;
    uint8_t* Bb = Ab + 16384;
    // A: 128 rows x 32 fp32 (1024 slots of 16B), XOR-preswizzled source
#pragma unroll
    for (int i = 0; i < 4; ++i) {
      int si = i * 256 + tid;
      int row = si >> 3, p = si & 7;
      gload16(x + (size_t)(m0 + row) * 1024 + k0 + ((p ^ (row & 7)) << 2), Ab + si * 16);
    }
    // B: 256 rows x 32 fp16 (1024 slots of 16B)
#pragma unroll
    for (int i = 0; i < 4; ++i) {
      int si = i * 256 + tid;
      int row = si >> 2, p = si & 3;
      gload16(Wt + (size_t)(n0 + row) * 1024 + k0 + ((p ^ (row & 3)) << 3), Bb + si * 16);
    }
  };

  stage(0, 0);
  __syncthreads();

  for (int kt = 0; kt < 32; ++kt) {
    int cur = kt & 1;
    if (kt < 31) stage((kt + 1) * 32, cur ^ 1);
    const uint8_t* Ab = smem + cur * 32768;
    const uint8_t* Bb = Ab + 16384;
    half8 af[4], bf[8];
#pragma unroll
    for (int mi = 0; mi < 4; ++mi) {
      int row = wr * 64 + mi * 16 + lr;
      const float* pa = (const float*)(Ab + row * 128);
      f32x4 a0 = *(const f32x4*)(pa + ((((lk << 1))     ^ (row & 7)) << 2));
      f32x4 a1 = *(const f32x4*)(pa + ((((lk << 1) | 1) ^ (row & 7)) << 2));
      half8 h;
#pragma unroll
      for (int j = 0; j < 4; ++j) { h[j] = (_Float16)a0[j]; h[j + 4] = (_Float16)a1[j]; }
      af[mi] = h;
    }
#pragma unroll
    for (int ni = 0; ni < 8; ++ni) {
      int row = wc * 128 + ni * 16 + lr;
      bf[ni] = *(const half8*)(Bb + row * 64 + ((lk ^ (row & 3)) << 4));
    }
#pragma unroll
    for (int mi = 0; mi < 4; ++mi)
#pragma unroll
      for (int ni = 0; ni < 8; ++ni)
        acc[mi][ni] = __builtin_amdgcn_mfma_f32_16x16x32_f16(af[mi], bf[ni], acc[mi][ni], 0, 0, 0);
    __syncthreads();
  }

  // ---- epilogues (C: col = lane&15 (n), row = (lane>>4)*4 + r (m)) ----
  if (by == 0) {
#pragma unroll
    for (int mi = 0; mi < 4; ++mi)
#pragma unroll
      for (int ni = 0; ni < 8; ++ni) {
        int nl = wc * 128 + ni * 16 + lr;
        int mg = m0 + wr * 64 + mi * 16 + lk * 4;
        float bias = bcat[nl];
#pragma unroll
        for (int r = 0; r < 4; ++r)
          Qh[(size_t)(mg + r) * DG + nl] = (_Float16)((acc[mi][ni][r] + bias) * 1.44269504f);
      }
  } else if (by == 2) {
#pragma unroll
    for (int mi = 0; mi < 4; ++mi)
#pragma unroll
      for (int ni = 0; ni < 8; ++ni) {
        int nl = wc * 128 + ni * 16 + lr;
        int mg = m0 + wr * 64 + mi * 16 + lk * 4;
        float bias = bcat[512 + nl];
        // V fragment-major: [b][st][dt][half hs][lane][8 j(t)]
        int dt = nl >> 5, lnv = nl & 31;
        int bb = mg >> 11, t0 = mg & 2047;
        int st = t0 >> 5, sp = t0 & 31;
        int hs = sp >> 4, gg = (sp >> 3) & 1, j0 = sp & 7;
        size_t idx = (size_t)(((bb * 64 + st) * 8 + dt) * 2 + hs) * 512
                   + (gg * 32 + lnv) * 8 + j0;
        half4v h;
#pragma unroll
        for (int r = 0; r < 4; ++r) h[r] = (_Float16)(acc[mi][ni][r] + bias);
        *(half4v*)(Vf + idx) = h;
      }
  } else {
    // K -> fragment-major via two 32KB LDS bounce phases (d-halves)
#pragma unroll
    for (int h = 0; h < 2; ++h) {
      if (wc == h) {
#pragma unroll
        for (int mi = 0; mi < 4; ++mi)
#pragma unroll
          for (int ni = 0; ni < 8; ++ni) {
            int dl = ni * 16 + lr;               // 0..127 within this half
            float bias = bcat[256 + h * 128 + dl];
#pragma unroll
            for (int r = 0; r < 4; ++r) {
              int t = wr * 64 + mi * 16 + lk * 4 + r;
              *(_Float16*)(smem + t * 256 + ((dl * 2) ^ ((t & 7) << 4))) =
                  (_Float16)(acc[mi][ni][r] + bias);
            }
          }
      }
      __syncthreads();
#pragma unroll
      for (int i = 0; i < 8; ++i) {
        int p = i * 256 + tid;
        int ln = p & 31, g = (p >> 5) & 1, cl = (p >> 6) & 7, st = p >> 9;
        int t = st * 32 + ln;
        int d0 = cl * 16 + g * 8;
        half8 v = *(const half8*)(smem + t * 256 + ((d0 * 2) ^ ((t & 7) << 4)));
        int tg = m0 + t;
        int bb = tg >> 11, stg = (tg & 2047) >> 5;
        int cc = h * 8 + cl;
        *(half8*)(Kf + ((size_t)(((bb * 64 + stg) * 16 + cc) * 2 + g) * 32 + ln) * 8) = v;
      }
      __syncthreads();
    }
  }
}

// ---- attn_main: 4 waves/WG d-split; K & V frag-major direct from L2; LDS = 20KB Sx only
// split-K: tiles 0-15 nc=1, 16-31 nc=2, 32-47 nc=3, 48-63 nc=4 (chunks <= 16 iters)
__global__ __launch_bounds__(256, 4) void attn_main(
    const _Float16* __restrict__ Qg, const _Float16* __restrict__ Kf,
    const _Float16* __restrict__ Vf, float* __restrict__ out,
    _Float16* __restrict__ PO, float* __restrict__ ML) {
  __shared__ float Sx[5120];      // [wv*64 + lane][20 floats] (16 data + pad)
  const int tid = threadIdx.x;
  const int wv = tid >> 6;        // 0..3
  const int l  = tid & 63;
  const int g  = l >> 5;
  const int ln = l & 31;
  const int id = blockIdx.x;
  const int b  = id & 7;                  // batch -> XCD pinning
  const int u  = id >> 3;                 // 0..159
  int tt, nc, c;
  if (u < 16)      { tt = u;                  nc = 1; c = 0; }
  else if (u < 48) { tt = 16 + ((u - 16) >> 1); nc = 2; c = (u - 16) & 1; }
  else if (u < 96) { tt = 32 + (u - 48) / 3;  nc = 3; c = (u - 48) % 3; }
  else             { tt = 48 + ((u - 96) >> 2); nc = 4; c = (u - 96) & 3; }
  const int len = (tt + nc) / nc;
  const int lo  = c * len;
  const int hi  = min(lo + len, tt + 1);
  const int q0  = tt * 32;

  const _Float16* Kfb = Kf + (size_t)b * 524288;
  const _Float16* Vfb = Vf + (size_t)b * 524288;

  const _Float16* Qrow = Qg + ((size_t)(b * T_ + q0 + ln)) * DG + wv * 64 + 8 * g;
  half8 qf[4];
#pragma unroll
  for (int j = 0; j < 4; ++j) qf[j] = *(const half8*)(Qrow + j * 16);

  f32x16 o0 = {}, o1 = {};        // output-d blocks dt = 2wv, 2wv+1
  float m_r = -1e30f, l_r = 0.0f;

  for (int kt = lo; kt < hi; ++kt) {
    // ---- K fragments: coalesced (frag-major) ----
    const _Float16* kbase = Kfb + (size_t)(kt * 16 + 4 * wv) * 512 + l * 8;
    half8 kf0 = *(const half8*)(kbase);
    half8 kf1 = *(const half8*)(kbase + 512);
    half8 kf2 = *(const half8*)(kbase + 1024);
    half8 kf3 = *(const half8*)(kbase + 1536);
    // ---- V fragments: coalesced, consumed after softmax ----
    const _Float16* vbase = Vfb + (size_t)(kt * 8 + 2 * wv) * 1024 + l * 8;
    half8 va0 = *(const half8*)(vbase);
    half8 va1 = *(const half8*)(vbase + 512);
    half8 vb0 = *(const half8*)(vbase + 1024);
    half8 vb1 = *(const half8*)(vbase + 1536);

    f32x16 s_acc = {};
    __builtin_amdgcn_s_setprio(1);
    s_acc = __builtin_amdgcn_mfma_f32_32x32x16_f16(kf0, qf[0], s_acc, 0, 0, 0);
    s_acc = __builtin_amdgcn_mfma_f32_32x32x16_f16(kf1, qf[1], s_acc, 0, 0, 0);
    s_acc = __builtin_amdgcn_mfma_f32_32x32x16_f16(kf2, qf[2], s_acc, 0, 0, 0);
    s_acc = __builtin_amdgcn_mfma_f32_32x32x16_f16(kf3, qf[3], s_acc, 0, 0, 0);
    __builtin_amdgcn_s_setprio(0);

    // ---- publish partial scores, exchange ----
    {
      float* myrow = Sx + (wv * 64 + l) * 20;
#pragma unroll
      for (int i = 0; i < 4; ++i)
        *(f32x4*)(myrow + 4 * i) = *(((const f32x4*)&s_acc) + i);
    }
    WAIT_LGKM0();
    __builtin_amdgcn_s_barrier();

    f32x4 sv[4];
#pragma unroll
    for (int i = 0; i < 4; ++i) sv[i] = *(((const f32x4*)&s_acc) + i);
#pragma unroll
    for (int wo = 0; wo < 4; ++wo) {
      if (wo == wv) continue;
      const float* prow = Sx + (wo * 64 + l) * 20;
#pragma unroll
      for (int i = 0; i < 4; ++i) sv[i] += *(const f32x4*)(prow + 4 * i);
    }
    float s[16];
#pragma unroll
    for (int r = 0; r < 16; ++r) s[r] = sv[r >> 2][r & 3];

    if (kt == tt) {                  // causal mask (last chunk only)
#pragma unroll
      for (int r = 0; r < 16; ++r) {
        int srow = (r & 3) + 8 * (r >> 2) + 4 * g;
        if (srow > ln) s[r] = -1e30f;
      }
    }
    // ---- softmax (replicated across waves, bit-identical) ----
    float pmax = s[0];
#pragma unroll
    for (int r = 1; r < 16; ++r) pmax = fmaxf(pmax, s[r]);
    pmax = fmaxf(pmax, cross32(pmax, g));
    if (!__all(pmax <= m_r + 8.0f)) {   // defer-max rescale (T13)
      float mnew = fmaxf(m_r, pmax);
      float sc = __builtin_amdgcn_exp2f(m_r - mnew);
      l_r *= sc;
#pragma unroll
      for (int r = 0; r < 16; ++r) { o0[r] *= sc; o1[r] *= sc; }
      m_r = mnew;
    }
    float p[16]; float psum = 0.0f;
#pragma unroll
    for (int r = 0; r < 16; ++r) { p[r] = __builtin_amdgcn_exp2f(s[r] - m_r); psum += p[r]; }
    l_r += psum + cross32(psum, g);

    // ---- P -> fp16 B-fragments: cvt_pkrtz + 4 permlane32_swap ----
    unsigned ph[8];
#pragma unroll
    for (int i = 0; i < 8; ++i) {
      fp16x2 t2 = __builtin_amdgcn_cvt_pkrtz(p[2 * i], p[2 * i + 1]);
      ph[i] = __builtin_bit_cast(unsigned, t2);
    }
    union U { unsigned u[4]; half8 h; };
    U f0, f1;
    {
      uint2v r02 = __builtin_amdgcn_permlane32_swap(ph[0], ph[2], false, false);
      uint2v r13 = __builtin_amdgcn_permlane32_swap(ph[1], ph[3], false, false);
      uint2v r46 = __builtin_amdgcn_permlane32_swap(ph[4], ph[6], false, false);
      uint2v r57 = __builtin_amdgcn_permlane32_swap(ph[5], ph[7], false, false);
      f0.u[0] = r02[0]; f0.u[2] = r02[1];
      f0.u[1] = r13[0]; f0.u[3] = r13[1];
      f1.u[0] = r46[0]; f1.u[2] = r46[1];
      f1.u[1] = r57[0]; f1.u[3] = r57[1];
    }

    // ---- PV for this wave's output-d slice ----
    __builtin_amdgcn_s_setprio(1);
    o0 = __builtin_amdgcn_mfma_f32_32x32x16_f16(va0, f0.h, o0, 0, 0, 0);
    o0 = __builtin_amdgcn_mfma_f32_32x32x16_f16(va1, f1.h, o0, 0, 0, 0);
    o1 = __builtin_amdgcn_mfma_f32_32x32x16_f16(vb0, f0.h, o1, 0, 0, 0);
    o1 = __builtin_amdgcn_mfma_f32_32x32x16_f16(vb1, f1.h, o1, 0, 0, 0);
    __builtin_amdgcn_s_setprio(0);

    __builtin_amdgcn_s_barrier();    // Sx safe to overwrite next iter
  }

  // ---- epilogue: per-wave chunk transpose in own Sx region ----
  float* chunk = Sx + wv * 1280;     // [32 q][33 d] fp32, wave-private
  if (nc == 1) {
    float inv = 1.0f / (l_r * 8.0f);           // includes post-softmax /sqrt(64)
    float* ob = out + ((size_t)(b * T_ + q0)) * 1024;
#pragma unroll
    for (int dtl = 0; dtl < 2; ++dtl) {
      const f32x16& oo = dtl ? o1 : o0;
      WAIT_LGKM0();
#pragma unroll
      for (int r = 0; r < 16; ++r) {
        int dl = (r & 3) + 8 * (r >> 2) + 4 * g;
        chunk[ln * 33 + dl] = oo[r] * inv;
      }
      WAIT_LGKM0();
#pragma unroll
      for (int rr = 0; rr < 2; ++rr) {
        int qq = (l >> 2) + 16 * rr;
        int cp = (l & 3) * 8;
        float vv[8];
#pragma unroll
        for (int jj = 0; jj < 8; ++jj) vv[jj] = chunk[qq * 33 + cp + jj];
        float4 w0 = make_float4(vv[0], vv[1], vv[2], vv[3]);
        float4 w1 = make_float4(vv[4], vv[5], vv[6], vv[7]);
        float* orow = ob + (size_t)qq * 1024 + (2 * wv + dtl) * 32 + cp;
#pragma unroll
        for (int rep = 0; rep < 4; ++rep) {
          *(float4*)(orow + rep * 256)     = w0;
          *(float4*)(orow + rep * 256 + 4) = w1;
        }
      }
    }
  } else {
    int ti = tt - 16;
    int off = (ti < 16) ? ti * 2 : (ti < 32) ? 32 + (ti - 16) * 3 : 80 + (ti - 32) * 4;
    int slot = b * 144 + off + c;
    _Float16* P = PO + (size_t)slot * 8192;
#pragma unroll
    for (int dtl = 0; dtl < 2; ++dtl) {
      const f32x16& oo = dtl ? o1 : o0;
      WAIT_LGKM0();
#pragma unroll
      for (int r = 0; r < 16; ++r) {
        int dl = (r & 3) + 8 * (r >> 2) + 4 * g;
        chunk[ln * 33 + dl] = oo[r];
      }
      WAIT_LGKM0();
#pragma unroll
      for (int rr = 0; rr < 2; ++rr) {
        int qq = (l >> 2) + 16 * rr;
        int cp = (l & 3) * 8;
        half8 hv;
#pragma unroll
        for (int jj = 0; jj < 8; ++jj) hv[jj] = (_Float16)chunk[qq * 33 + cp + jj];
        *(half8*)(P + qq * 256 + (2 * wv + dtl) * 32 + cp) = hv;
      }
    }
    if (wv == 0 && l < 32) {
      ML[(size_t)slot * 64 + l]      = m_r;
      ML[(size_t)slot * 64 + 32 + l] = l_r;
    }
  }
}

// ---- attn_merge: combine nc in {2,3,4} fp16 partials, normalize, x4 replicate ----
__global__ __launch_bounds__(256) void attn_merge(
    const _Float16* __restrict__ PO, const float* __restrict__ ML,
    float* __restrict__ out) {
  const int id = blockIdx.x;           // 384 = 8 b x 48 tiles
  const int b = id & 7, ti = id >> 3;
  const int tt = 16 + ti;
  const int nc = (ti < 16) ? 2 : (ti < 32) ? 3 : 4;
  const int off = (ti < 16) ? ti * 2 : (ti < 32) ? 32 + (ti - 16) * 3 : 80 + (ti - 32) * 4;
  const int slot0 = b * 144 + off;
  const int tid = threadIdx.x;
  const int row = tid >> 3, cb = tid & 7;

  float mj[4], lj[4];
  float M = -1e30f;
#pragma unroll
  for (int j = 0; j < 4; ++j)
    if (j < nc) {
      mj[j] = ML[(size_t)(slot0 + j) * 64 + row];
      lj[j] = ML[(size_t)(slot0 + j) * 64 + 32 + row];
      M = fmaxf(M, mj[j]);
    }
  float sc[4], lsum = 0.0f;
#pragma unroll
  for (int j = 0; j < 4; ++j)
    if (j < nc) { sc[j] = __builtin_amdgcn_exp2f(mj[j] - M); lsum += lj[j] * sc[j]; }
  float inv = 1.0f / (lsum * 8.0f);    // includes post-softmax /sqrt(64)

  float acc[32] = {};
#pragma unroll
  for (int j = 0; j < 4; ++j)
    if (j < nc) {
      const _Float16* P = PO + (size_t)(slot0 + j) * 8192 + row * 256 + cb * 32;
      float s = sc[j];
#pragma unroll
      for (int q = 0; q < 4; ++q) {
        half8 h = *(const half8*)(P + q * 8);
#pragma unroll
        for (int e = 0; e < 8; ++e) acc[q * 8 + e] += s * (float)h[e];
      }
    }
  float* orow = out + ((size_t)(b * T_ + tt * 32 + row)) * 1024 + cb * 32;
#pragma unroll
  for (int q = 0; q < 8; ++q) {
    float4 v;
    v.x = acc[q * 4 + 0] * inv; v.y = acc[q * 4 + 1] * inv;
    v.z = acc[q * 4 + 2] * inv; v.w = acc[q * 4 + 3] * inv;
#pragma unroll
    for (int rep = 0; rep < 4; ++rep)
      *(float4*)(orow + rep * 256 + q * 4) = v;
  }
}

extern "C" void kernel_launch(void* const* d_in, const int* in_sizes, int n_in,
                              void* d_out, int out_size, void* d_ws, size_t ws_size,
                              hipStream_t stream) {
  const float* x  = (const float*)d_in[0];
  const float* Wq = (const float*)d_in[1];
  const float* bq = (const float*)d_in[2];
  const float* Wk = (const float*)d_in[3];
  const float* bk = (const float*)d_in[4];
  const float* Wv = (const float*)d_in[5];
  const float* bv = (const float*)d_in[6];
  float* out = (float*)d_out;
  char* ws = (char*)d_ws;
  _Float16* Wt   = (_Float16*)ws;                         // 1.5 MB
  float*    bcat = (float*)(ws + 0x180000);               // 4 KB
  _Float16* Qh   = (_Float16*)(ws + 0x181000);            // 8 MB
  _Float16* Kf   = (_Float16*)(ws + 0x981000);            // 8 MB fragment-major K
  _Float16* Vf   = (_Float16*)(ws + 0x1181000);           // 8 MB fragment-major V
  _Float16* PO   = (_Float16*)(ws + 0x1981000);           // 18.9 MB partials
  float*    ML   = (float*)(ws + 0x1981000 + 0x1200000);  // 0.3 MB

  prep_w<<<768, 256, 0, stream>>>(Wq, bq, Wk, bk, Wv, bv, Wt, bcat);
  qkv_gemm<<<dim3(128, 3), 256, 0, stream>>>(x, Wt, bcat, Qh, Kf, Vf);
  attn_main<<<1280, 256, 0, stream>>>(Qh, Kf, Vf, out, PO, ML);
  attn_merge<<<384, 256, 0, stream>>>(PO, ML, out);
}

// Round 14
// 148.877 us; speedup vs baseline: 1.2464x; 1.0689x over previous
//
#include <hip/hip_runtime.h>
#include <float.h>
#include <stdint.h>

#define T_ 2048
#define DG 256   // folded/group width: 4 groups * 64

typedef _Float16 half8 __attribute__((ext_vector_type(8)));
typedef _Float16 half4v __attribute__((ext_vector_type(4)));
typedef __fp16 fp16x2 __attribute__((ext_vector_type(2)));
typedef float f32x4 __attribute__((ext_vector_type(4)));
typedef float f32x16 __attribute__((ext_vector_type(16)));
typedef unsigned uint2v __attribute__((ext_vector_type(2)));

__device__ __forceinline__ void gload16(const void* g, void* l) {
  __builtin_amdgcn_global_load_lds(
      (const __attribute__((address_space(1))) unsigned int*)g,
      (__attribute__((address_space(3))) unsigned int*)l, 16, 0, 0);
}
#define WAIT_LGKM0() do { asm volatile("s_waitcnt lgkmcnt(0)" ::: "memory"); __builtin_amdgcn_sched_barrier(0); } while (0)

// lane<->lane^32 exchange, all-VALU (v_permlane32_swap_b32)
__device__ __forceinline__ float cross32(float x, int g) {
  unsigned u = __builtin_bit_cast(unsigned, x);
  uint2v r = __builtin_amdgcn_permlane32_swap(u, u, false, false);
  return __builtin_bit_cast(float, g ? r[0] : r[1]);
}

// ---- prep_w: Wt[768][1024] fp16 (folded Wq | Wk | Wv, transposed) + bcat[768] f32 ----
__global__ __launch_bounds__(256) void prep_w(
    const float* __restrict__ Wq, const float* __restrict__ bq,
    const float* __restrict__ Wk, const float* __restrict__ bk,
    const float* __restrict__ Wv, const float* __restrict__ bv,
    _Float16* __restrict__ Wt, float* __restrict__ bcat) {
  for (int idx = blockIdx.x * 256 + threadIdx.x; idx < 786432; idx += 768 * 256) {
    int n = idx >> 10, k = idx & 1023;
    float v;
    if (n < 256)      v = Wq[k * 1024 + n] + Wq[k * 1024 + n + 256]
                        + Wq[k * 1024 + n + 512] + Wq[k * 1024 + n + 768];
    else if (n < 512) v = Wk[k * 256 + n - 256];
    else              v = Wv[k * 256 + n - 512];
    Wt[idx] = (_Float16)v;
    if (k == 0) {
      float bb;
      if (n < 256)      bb = bq[n] + bq[n + 256] + bq[n + 512] + bq[n + 768];
      else if (n < 512) bb = bk[n - 256];
      else              bb = bv[n - 512];
      bcat[n] = bb;
    }
  }
}

// ---- qkv_gemm: x[16384x1024] fp32 @ Wt^T -> Q fp16(x log2e) | K frag-major | V frag-major
// 128x128 tile (grid 128 x 6 = 3 types x 2 n-halves); A fp32 + B fp16 via global_load_lds;
// A converted to fp16 at fragment read (RNE). 48KB LDS -> 3 WG/CU.
__global__ __launch_bounds__(256) void qkv_gemm(
    const float* __restrict__ x, const _Float16* __restrict__ Wt,
    const float* __restrict__ bcat,
    _Float16* __restrict__ Qh, _Float16* __restrict__ Kf, _Float16* __restrict__ Vf) {
  __shared__ __align__(16) uint8_t smem[49152];   // 2 x (A 16KB fp32 + B 8KB fp16)
  const int tid = threadIdx.x;
  const int w = tid >> 6, l = tid & 63;
  const int wr = w >> 1, wc = w & 1;
  const int lr = l & 15, lk = l >> 4;
  const int m0 = blockIdx.x * 128;
  const int by = blockIdx.y >> 1;     // 0=Q, 1=K, 2=V
  const int nh = blockIdx.y & 1;      // n-half within type

  f32x4 acc[4][4] = {};

  auto stage = [&](int k0, int buf) {
    uint8_t* Ab = smem + buf * 24576;
    uint8_t* Bb = Ab + 16384;
    // A: 128 rows x 32 fp32 (1024 slots of 16B), XOR-preswizzled source
#pragma unroll
    for (int i = 0; i < 4; ++i) {
      int si = i * 256 + tid;
      int row = si >> 3, p = si & 7;
      gload16(x + (size_t)(m0 + row) * 1024 + k0 + ((p ^ (row & 7)) << 2), Ab + si * 16);
    }
    // B: 128 rows x 32 fp16 (512 slots of 16B)
#pragma unroll
    for (int i = 0; i < 2; ++i) {
      int si = i * 256 + tid;
      int row = si >> 2, p = si & 3;
      gload16(Wt + (size_t)(by * 256 + nh * 128 + row) * 1024 + k0 + ((p ^ (row & 3)) << 3),
              Bb + si * 16);
    }
  };

  stage(0, 0);
  __syncthreads();

  for (int kt = 0; kt < 32; ++kt) {
    int cur = kt & 1;
    if (kt < 31) stage((kt + 1) * 32, cur ^ 1);
    const uint8_t* Ab = smem + cur * 24576;
    const uint8_t* Bb = Ab + 16384;
    half8 af[4], bf[4];
#pragma unroll
    for (int mi = 0; mi < 4; ++mi) {
      int row = wr * 64 + mi * 16 + lr;
      const float* pa = (const float*)(Ab + row * 128);
      f32x4 a0 = *(const f32x4*)(pa + ((((lk << 1))     ^ (row & 7)) << 2));
      f32x4 a1 = *(const f32x4*)(pa + ((((lk << 1) | 1) ^ (row & 7)) << 2));
      half8 h;
#pragma unroll
      for (int j = 0; j < 4; ++j) { h[j] = (_Float16)a0[j]; h[j + 4] = (_Float16)a1[j]; }
      af[mi] = h;
    }
#pragma unroll
    for (int ni = 0; ni < 4; ++ni) {
      int row = wc * 64 + ni * 16 + lr;
      bf[ni] = *(const half8*)(Bb + row * 64 + ((lk ^ (row & 3)) << 4));
    }
#pragma unroll
    for (int mi = 0; mi < 4; ++mi)
#pragma unroll
      for (int ni = 0; ni < 4; ++ni)
        acc[mi][ni] = __builtin_amdgcn_mfma_f32_16x16x32_f16(af[mi], bf[ni], acc[mi][ni], 0, 0, 0);
    __syncthreads();
  }

  // ---- epilogues (C: col = lane&15 (n), row = (lane>>4)*4 + r (m)) ----
  if (by == 0) {
#pragma unroll
    for (int mi = 0; mi < 4; ++mi)
#pragma unroll
      for (int ni = 0; ni < 4; ++ni) {
        int nl = nh * 128 + wc * 64 + ni * 16 + lr;
        int mg = m0 + wr * 64 + mi * 16 + lk * 4;
        float bias = bcat[nl];
#pragma unroll
        for (int r = 0; r < 4; ++r)
          Qh[(size_t)(mg + r) * DG + nl] = (_Float16)((acc[mi][ni][r] + bias) * 1.44269504f);
      }
  } else if (by == 2) {
#pragma unroll
    for (int mi = 0; mi < 4; ++mi)
#pragma unroll
      for (int ni = 0; ni < 4; ++ni) {
        int nl = nh * 128 + wc * 64 + ni * 16 + lr;
        int mg = m0 + wr * 64 + mi * 16 + lk * 4;
        float bias = bcat[512 + nl];
        // V fragment-major: [b][st][dt][half hs][lane][8 j(t)]
        int dt = nl >> 5, lnv = nl & 31;
        int bb = mg >> 11, t0 = mg & 2047;
        int st = t0 >> 5, sp = t0 & 31;
        int hs = sp >> 4, gg = (sp >> 3) & 1, j0 = sp & 7;
        size_t idx = (size_t)(((bb * 64 + st) * 8 + dt) * 2 + hs) * 512
                   + (gg * 32 + lnv) * 8 + j0;
        half4v h;
#pragma unroll
        for (int r = 0; r < 4; ++r) h[r] = (_Float16)(acc[mi][ni][r] + bias);
        *(half4v*)(Vf + idx) = h;
      }
  } else {
    // K -> fragment-major via 32KB LDS bounce (single phase at 128x128)
#pragma unroll
    for (int mi = 0; mi < 4; ++mi)
#pragma unroll
      for (int ni = 0; ni < 4; ++ni) {
        int dl = wc * 64 + ni * 16 + lr;           // 0..127 local d
        float bias = bcat[256 + nh * 128 + dl];
#pragma unroll
        for (int r = 0; r < 4; ++r) {
          int t = wr * 64 + mi * 16 + lk * 4 + r;
          *(_Float16*)(smem + t * 256 + ((dl * 2) ^ ((t & 7) << 4))) =
              (_Float16)(acc[mi][ni][r] + bias);
        }
      }
    __syncthreads();
#pragma unroll
    for (int i = 0; i < 8; ++i) {
      int p = i * 256 + tid;
      int ln = p & 31, g = (p >> 5) & 1, cl = (p >> 6) & 7, st = p >> 9;
      int t = st * 32 + ln;
      int d0 = cl * 16 + g * 8;
      half8 v = *(const half8*)(smem + t * 256 + ((d0 * 2) ^ ((t & 7) << 4)));
      int tg = m0 + t;
      int bb = tg >> 11, stg = (tg & 2047) >> 5;
      int cc = nh * 8 + cl;
      *(half8*)(Kf + ((size_t)(((bb * 64 + stg) * 16 + cc) * 2 + g) * 32 + ln) * 8) = v;
    }
  }
}

// ---- attn_main: 4 waves/WG d-split; K & V frag-major direct from L2; LDS = 20KB Sx only
// split-K: tiles 0-15 nc=1, 16-31 nc=2, 32-47 nc=3, 48-63 nc=4 (chunks <= 16 iters)
__global__ __launch_bounds__(256, 4) void attn_main(
    const _Float16* __restrict__ Qg, const _Float16* __restrict__ Kf,
    const _Float16* __restrict__ Vf, float* __restrict__ out,
    _Float16* __restrict__ PO, float* __restrict__ ML) {
  __shared__ float Sx[5120];      // [wv*64 + lane][20 floats] (16 data + pad)
  const int tid = threadIdx.x;
  const int wv = tid >> 6;        // 0..3
  const int l  = tid & 63;
  const int g  = l >> 5;
  const int ln = l & 31;
  const int id = blockIdx.x;
  const int b  = id & 7;                  // batch -> XCD pinning
  const int u  = id >> 3;                 // 0..159
  int tt, nc, c;
  if (u < 16)      { tt = u;                  nc = 1; c = 0; }
  else if (u < 48) { tt = 16 + ((u - 16) >> 1); nc = 2; c = (u - 16) & 1; }
  else if (u < 96) { tt = 32 + (u - 48) / 3;  nc = 3; c = (u - 48) % 3; }
  else             { tt = 48 + ((u - 96) >> 2); nc = 4; c = (u - 96) & 3; }
  const int len = (tt + nc) / nc;
  const int lo  = c * len;
  const int hi  = min(lo + len, tt + 1);
  const int q0  = tt * 32;

  const _Float16* Kfb = Kf + (size_t)b * 524288;
  const _Float16* Vfb = Vf + (size_t)b * 524288;

  const _Float16* Qrow = Qg + ((size_t)(b * T_ + q0 + ln)) * DG + wv * 64 + 8 * g;
  half8 qf[4];
#pragma unroll
  for (int j = 0; j < 4; ++j) qf[j] = *(const half8*)(Qrow + j * 16);

  f32x16 o0 = {}, o1 = {};        // output-d blocks dt = 2wv, 2wv+1
  float m_r = -1e30f, l_r = 0.0f;

  for (int kt = lo; kt < hi; ++kt) {
    // ---- K fragments: coalesced (frag-major) ----
    const _Float16* kbase = Kfb + (size_t)(kt * 16 + 4 * wv) * 512 + l * 8;
    half8 kf0 = *(const half8*)(kbase);
    half8 kf1 = *(const half8*)(kbase + 512);
    half8 kf2 = *(const half8*)(kbase + 1024);
    half8 kf3 = *(const half8*)(kbase + 1536);
    // ---- V fragments: coalesced, consumed after softmax ----
    const _Float16* vbase = Vfb + (size_t)(kt * 8 + 2 * wv) * 1024 + l * 8;
    half8 va0 = *(const half8*)(vbase);
    half8 va1 = *(const half8*)(vbase + 512);
    half8 vb0 = *(const half8*)(vbase + 1024);
    half8 vb1 = *(const half8*)(vbase + 1536);

    f32x16 s_acc = {};
    __builtin_amdgcn_s_setprio(1);
    s_acc = __builtin_amdgcn_mfma_f32_32x32x16_f16(kf0, qf[0], s_acc, 0, 0, 0);
    s_acc = __builtin_amdgcn_mfma_f32_32x32x16_f16(kf1, qf[1], s_acc, 0, 0, 0);
    s_acc = __builtin_amdgcn_mfma_f32_32x32x16_f16(kf2, qf[2], s_acc, 0, 0, 0);
    s_acc = __builtin_amdgcn_mfma_f32_32x32x16_f16(kf3, qf[3], s_acc, 0, 0, 0);
    __builtin_amdgcn_s_setprio(0);

    // ---- publish partial scores, exchange ----
    {
      float* myrow = Sx + (wv * 64 + l) * 20;
#pragma unroll
      for (int i = 0; i < 4; ++i)
        *(f32x4*)(myrow + 4 * i) = *(((const f32x4*)&s_acc) + i);
    }
    WAIT_LGKM0();
    __builtin_amdgcn_s_barrier();

    f32x4 sv[4];
#pragma unroll
    for (int i = 0; i < 4; ++i) sv[i] = *(((const f32x4*)&s_acc) + i);
#pragma unroll
    for (int wo = 0; wo < 4; ++wo) {
      if (wo == wv) continue;
      const float* prow = Sx + (wo * 64 + l) * 20;
#pragma unroll
      for (int i = 0; i < 4; ++i) sv[i] += *(const f32x4*)(prow + 4 * i);
    }
    float s[16];
#pragma unroll
    for (int r = 0; r < 16; ++r) s[r] = sv[r >> 2][r & 3];

    if (kt == tt) {                  // causal mask (last chunk only)
#pragma unroll
      for (int r = 0; r < 16; ++r) {
        int srow = (r & 3) + 8 * (r >> 2) + 4 * g;
        if (srow > ln) s[r] = -1e30f;
      }
    }
    // ---- softmax (replicated across waves, bit-identical) ----
    float pmax = s[0];
#pragma unroll
    for (int r = 1; r < 16; ++r) pmax = fmaxf(pmax, s[r]);
    pmax = fmaxf(pmax, cross32(pmax, g));
    if (!__all(pmax <= m_r + 8.0f)) {   // defer-max rescale (T13)
      float mnew = fmaxf(m_r, pmax);
      float sc = __builtin_amdgcn_exp2f(m_r - mnew);
      l_r *= sc;
#pragma unroll
      for (int r = 0; r < 16; ++r) { o0[r] *= sc; o1[r] *= sc; }
      m_r = mnew;
    }
    float p[16]; float psum = 0.0f;
#pragma unroll
    for (int r = 0; r < 16; ++r) { p[r] = __builtin_amdgcn_exp2f(s[r] - m_r); psum += p[r]; }
    l_r += psum + cross32(psum, g);

    // ---- P -> fp16 B-fragments: cvt_pkrtz + 4 permlane32_swap ----
    unsigned ph[8];
#pragma unroll
    for (int i = 0; i < 8; ++i) {
      fp16x2 t2 = __builtin_amdgcn_cvt_pkrtz(p[2 * i], p[2 * i + 1]);
      ph[i] = __builtin_bit_cast(unsigned, t2);
    }
    union U { unsigned u[4]; half8 h; };
    U f0, f1;
    {
      uint2v r02 = __builtin_amdgcn_permlane32_swap(ph[0], ph[2], false, false);
      uint2v r13 = __builtin_amdgcn_permlane32_swap(ph[1], ph[3], false, false);
      uint2v r46 = __builtin_amdgcn_permlane32_swap(ph[4], ph[6], false, false);
      uint2v r57 = __builtin_amdgcn_permlane32_swap(ph[5], ph[7], false, false);
      f0.u[0] = r02[0]; f0.u[2] = r02[1];
      f0.u[1] = r13[0]; f0.u[3] = r13[1];
      f1.u[0] = r46[0]; f1.u[2] = r46[1];
      f1.u[1] = r57[0]; f1.u[3] = r57[1];
    }

    // ---- PV for this wave's output-d slice ----
    __builtin_amdgcn_s_setprio(1);
    o0 = __builtin_amdgcn_mfma_f32_32x32x16_f16(va0, f0.h, o0, 0, 0, 0);
    o0 = __builtin_amdgcn_mfma_f32_32x32x16_f16(va1, f1.h, o0, 0, 0, 0);
    o1 = __builtin_amdgcn_mfma_f32_32x32x16_f16(vb0, f0.h, o1, 0, 0, 0);
    o1 = __builtin_amdgcn_mfma_f32_32x32x16_f16(vb1, f1.h, o1, 0, 0, 0);
    __builtin_amdgcn_s_setprio(0);

    __builtin_amdgcn_s_barrier();    // Sx safe to overwrite next iter
  }

  // ---- epilogue: per-wave chunk transpose in own Sx region ----
  float* chunk = Sx + wv * 1280;     // [32 q][33 d] fp32, wave-private
  if (nc == 1) {
    float inv = 1.0f / (l_r * 8.0f);           // includes post-softmax /sqrt(64)
    float* ob = out + ((size_t)(b * T_ + q0)) * 1024;
#pragma unroll
    for (int dtl = 0; dtl < 2; ++dtl) {
      const f32x16& oo = dtl ? o1 : o0;
      WAIT_LGKM0();
#pragma unroll
      for (int r = 0; r < 16; ++r) {
        int dl = (r & 3) + 8 * (r >> 2) + 4 * g;
        chunk[ln * 33 + dl] = oo[r] * inv;
      }
      WAIT_LGKM0();
#pragma unroll
      for (int rr = 0; rr < 2; ++rr) {
        int qq = (l >> 2) + 16 * rr;
        int cp = (l & 3) * 8;
        float vv[8];
#pragma unroll
        for (int jj = 0; jj < 8; ++jj) vv[jj] = chunk[qq * 33 + cp + jj];
        float4 w0 = make_float4(vv[0], vv[1], vv[2], vv[3]);
        float4 w1 = make_float4(vv[4], vv[5], vv[6], vv[7]);
        float* orow = ob + (size_t)qq * 1024 + (2 * wv + dtl) * 32 + cp;
#pragma unroll
        for (int rep = 0; rep < 4; ++rep) {
          *(float4*)(orow + rep * 256)     = w0;
          *(float4*)(orow + rep * 256 + 4) = w1;
        }
      }
    }
  } else {
    int ti = tt - 16;
    int off = (ti < 16) ? ti * 2 : (ti < 32) ? 32 + (ti - 16) * 3 : 80 + (ti - 32) * 4;
    int slot = b * 144 + off + c;
    _Float16* P = PO + (size_t)slot * 8192;
#pragma unroll
    for (int dtl = 0; dtl < 2; ++dtl) {
      const f32x16& oo = dtl ? o1 : o0;
      WAIT_LGKM0();
#pragma unroll
      for (int r = 0; r < 16; ++r) {
        int dl = (r & 3) + 8 * (r >> 2) + 4 * g;
        chunk[ln * 33 + dl] = oo[r];
      }
      WAIT_LGKM0();
#pragma unroll
      for (int rr = 0; rr < 2; ++rr) {
        int qq = (l >> 2) + 16 * rr;
        int cp = (l & 3) * 8;
        half8 hv;
#pragma unroll
        for (int jj = 0; jj < 8; ++jj) hv[jj] = (_Float16)chunk[qq * 33 + cp + jj];
        *(half8*)(P + qq * 256 + (2 * wv + dtl) * 32 + cp) = hv;
      }
    }
    if (wv == 0 && l < 32) {
      ML[(size_t)slot * 64 + l]      = m_r;
      ML[(size_t)slot * 64 + 32 + l] = l_r;
    }
  }
}

// ---- attn_merge: combine nc in {2,3,4} fp16 partials, normalize, x4 replicate ----
__global__ __launch_bounds__(256) void attn_merge(
    const _Float16* __restrict__ PO, const float* __restrict__ ML,
    float* __restrict__ out) {
  const int id = blockIdx.x;           // 384 = 8 b x 48 tiles
  const int b = id & 7, ti = id >> 3;
  const int tt = 16 + ti;
  const int nc = (ti < 16) ? 2 : (ti < 32) ? 3 : 4;
  const int off = (ti < 16) ? ti * 2 : (ti < 32) ? 32 + (ti - 16) * 3 : 80 + (ti - 32) * 4;
  const int slot0 = b * 144 + off;
  const int tid = threadIdx.x;
  const int row = tid >> 3, cb = tid & 7;

  float mj[4], lj[4];
  float M = -1e30f;
#pragma unroll
  for (int j = 0; j < 4; ++j)
    if (j < nc) {
      mj[j] = ML[(size_t)(slot0 + j) * 64 + row];
      lj[j] = ML[(size_t)(slot0 + j) * 64 + 32 + row];
      M = fmaxf(M, mj[j]);
    }
  float sc[4], lsum = 0.0f;
#pragma unroll
  for (int j = 0; j < 4; ++j)
    if (j < nc) { sc[j] = __builtin_amdgcn_exp2f(mj[j] - M); lsum += lj[j] * sc[j]; }
  float inv = 1.0f / (lsum * 8.0f);    // includes post-softmax /sqrt(64)

  float acc[32] = {};
#pragma unroll
  for (int j = 0; j < 4; ++j)
    if (j < nc) {
      const _Float16* P = PO + (size_t)(slot0 + j) * 8192 + row * 256 + cb * 32;
      float s = sc[j];
#pragma unroll
      for (int q = 0; q < 4; ++q) {
        half8 h = *(const half8*)(P + q * 8);
#pragma unroll
        for (int e = 0; e < 8; ++e) acc[q * 8 + e] += s * (float)h[e];
      }
    }
  float* orow = out + ((size_t)(b * T_ + tt * 32 + row)) * 1024 + cb * 32;
#pragma unroll
  for (int q = 0; q < 8; ++q) {
    float4 v;
    v.x = acc[q * 4 + 0] * inv; v.y = acc[q * 4 + 1] * inv;
    v.z = acc[q * 4 + 2] * inv; v.w = acc[q * 4 + 3] * inv;
#pragma unroll
    for (int rep = 0; rep < 4; ++rep)
      *(float4*)(orow + rep * 256 + q * 4) = v;
  }
}

extern "C" void kernel_launch(void* const* d_in, const int* in_sizes, int n_in,
                              void* d_out, int out_size, void* d_ws, size_t ws_size,
                              hipStream_t stream) {
  const float* x  = (const float*)d_in[0];
  const float* Wq = (const float*)d_in[1];
  const float* bq = (const float*)d_in[2];
  const float* Wk = (const float*)d_in[3];
  const float* bk = (const float*)d_in[4];
  const float* Wv = (const float*)d_in[5];
  const float* bv = (const float*)d_in[6];
  float* out = (float*)d_out;
  char* ws = (char*)d_ws;
  _Float16* Wt   = (_Float16*)ws;                         // 1.5 MB
  float*    bcat = (float*)(ws + 0x180000);               // 4 KB
  _Float16* Qh   = (_Float16*)(ws + 0x181000);            // 8 MB
  _Float16* Kf   = (_Float16*)(ws + 0x981000);            // 8 MB fragment-major K
  _Float16* Vf   = (_Float16*)(ws + 0x1181000);           // 8 MB fragment-major V
  _Float16* PO   = (_Float16*)(ws + 0x1981000);           // 18.9 MB partials
  float*    ML   = (float*)(ws + 0x1981000 + 0x1200000);  // 0.3 MB

  prep_w<<<768, 256, 0, stream>>>(Wq, bq, Wk, bk, Wv, bv, Wt, bcat);
  qkv_gemm<<<dim3(128, 6), 256, 0, stream>>>(x, Wt, bcat, Qh, Kf, Vf);
  attn_main<<<1280, 256, 0, stream>>>(Qh, Kf, Vf, out, PO, ML);
  attn_merge<<<384, 256, 0, stream>>>(PO, ML, out);
}